// Round 4
// baseline (128.985 us; speedup 1.0000x reference)
//
#include <hip/hip_runtime.h>

// SpMM: out[r, :] = sum_{e: row[e]==r} vals[e] * embeds[col[e], :]
// N_NODES=50000, N_EDGES=800000, D=64. row_idx is SORTED.
//
// Phase 1: build row_ptr[N_NODES+1] in d_ws.
// Phase 2 (L2-sliced): the 12.8MB embeds table misses per-XCD L2 (4MiB), so
//   round-3's gather was L3-bound (~25us). Split D into 4 slices of 16 floats
//   (64B, line-aligned). slice = (blockIdx%8)&3 -> with round-robin block->XCD
//   dispatch each XCD touches only a 3.2MB slice sub-table, which FITS its L2.
//   Gathers then run at L2 bandwidth. Correctness does not depend on the XCD
//   mapping (every (row,slice) is computed exactly once regardless).
//
//   Wave layout: one wave per (row, slice). g = lane>>2 (16 edge slots),
//   h = lane&3 (float4 within the 64B slice). One wave-load gathers
//   16 edges x 64B = 1KB. Butterfly-reduce over g (xor 4/8/16/32); lanes
//   g==0 store the 64B slice of the output row. Every (row,slice) is
//   written (empty rows -> 0), so no output memset.

constexpr int N_NODES = 50000;
constexpr int N_EDGES = 800000;
constexpr int D_FEAT  = 64;

__global__ __launch_bounds__(256) void build_row_ptr_kernel(
    const int* __restrict__ row_idx,
    int*       __restrict__ row_ptr)
{
    const int e = blockIdx.x * blockDim.x + threadIdx.x;
    if (e >= N_EDGES) return;
    const int r     = row_idx[e];
    const int rprev = (e == 0) ? -1 : row_idx[e - 1];
    for (int q = rprev + 1; q <= r; ++q) row_ptr[q] = e;   // fills empty rows too
    if (e == N_EDGES - 1) {
        for (int q = r + 1; q <= N_NODES; ++q) row_ptr[q] = N_EDGES;
    }
}

__global__ __launch_bounds__(256) void gcn_spmm_sliced_kernel(
    const int*   __restrict__ row_ptr,
    const int*   __restrict__ col_idx,
    const float* __restrict__ vals,
    const float* __restrict__ embeds,
    float*       __restrict__ out)
{
    // Block -> (slice, row-group) so that each XCD (blockIdx % 8, presumed
    // round-robin) sees exactly one feature slice.
    const int b = blockIdx.x;
    const int x = b & 7;                 // presumed XCD id
    const int s = x & 3;                 // feature slice 0..3
    const int i = ((b >> 3) << 1) + (x >> 2);          // block idx within slice
    const int row = (i << 2) + (threadIdx.x >> 6);     // 4 rows per block
    if (row >= N_NODES) return;

    const int lane = threadIdx.x & 63;
    const int g    = lane >> 2;          // edge slot (16 per wave)
    const int h    = lane & 3;           // float4 within 64B slice

    const int s_ = row_ptr[row];
    const int e_ = row_ptr[row + 1];

    const float4* __restrict__ emb4 = (const float4*)embeds;  // 16 float4 per row

    float4 acc = make_float4(0.f, 0.f, 0.f, 0.f);

    for (int base = s_; base < e_; base += 16) {
        const int   edge = base + g;
        const int   ce   = (edge < e_) ? edge : (e_ - 1);   // clamp, in-bounds
        const int   c    = col_idx[ce];
        const float v    = (edge < e_) ? vals[ce] : 0.f;
        const float4 gv  = emb4[c * 16 + s * 4 + h];        // 64B/edge slice gather
        acc.x += v * gv.x;
        acc.y += v * gv.y;
        acc.z += v * gv.z;
        acc.w += v * gv.w;
    }

    // Reduce over the 16 edge slots (lane bits 2..5).
    acc.x += __shfl_xor(acc.x, 4);  acc.y += __shfl_xor(acc.y, 4);
    acc.z += __shfl_xor(acc.z, 4);  acc.w += __shfl_xor(acc.w, 4);
    acc.x += __shfl_xor(acc.x, 8);  acc.y += __shfl_xor(acc.y, 8);
    acc.z += __shfl_xor(acc.z, 8);  acc.w += __shfl_xor(acc.w, 8);
    acc.x += __shfl_xor(acc.x, 16); acc.y += __shfl_xor(acc.y, 16);
    acc.z += __shfl_xor(acc.z, 16); acc.w += __shfl_xor(acc.w, 16);
    acc.x += __shfl_xor(acc.x, 32); acc.y += __shfl_xor(acc.y, 32);
    acc.z += __shfl_xor(acc.z, 32); acc.w += __shfl_xor(acc.w, 32);

    if (g == 0) {
        ((float4*)out)[row * 16 + s * 4 + h] = acc;   // 64B store per wave
    }
}

extern "C" void kernel_launch(void* const* d_in, const int* in_sizes, int n_in,
                              void* d_out, int out_size, void* d_ws, size_t ws_size,
                              hipStream_t stream) {
    const int*   row_idx = (const int*)  d_in[0];
    const int*   col_idx = (const int*)  d_in[1];
    const float* vals    = (const float*)d_in[2];
    const float* embeds  = (const float*)d_in[3];
    float*       out     = (float*)      d_out;
    int*         row_ptr = (int*)        d_ws;   // N_NODES+1 ints = ~200 KB

    {
        const int block  = 256;
        const int blocks = (N_EDGES + block - 1) / block;  // 3125
        build_row_ptr_kernel<<<blocks, block, 0, stream>>>(row_idx, row_ptr);
    }
    {
        // 4 slices x 12500 row-groups (4 rows each) = 50000 blocks (mult. of 8).
        const int block  = 256;
        const int blocks = 50000;
        gcn_spmm_sliced_kernel<<<blocks, block, 0, stream>>>(row_ptr, col_idx, vals,
                                                             embeds, out);
    }
}

// Round 5
// 111.740 us; speedup vs baseline: 1.1543x; 1.1543x over previous
//
#include <hip/hip_runtime.h>
#include <hip/hip_fp16.h>

// SpMM: out[r, :] = sum_{e: row[e]==r} vals[e] * embeds[col[e], :]
// N_NODES=50000, N_EDGES=800000, D=64. row_idx is SORTED.
//
// Round-4 post-mortem: 64B slices at 256B stride thrashed L2 (128B lines pull
// the neighboring slice -> footprint stayed 6.4MB/XCD) and FETCH exploded.
// Round-5 plan:
//   Kernel 1 (fused prep, streaming):
//     - build row_ptr[N_NODES+1] in d_ws
//     - convert embeds fp32 -> fp16 and PHYSICALLY split into two contiguous
//       tables tbl[s][50000 x 32 halves] = 3.2 MB each (fits 4MiB per-XCD L2,
//       zero stride waste).
//   Kernel 2 (spmm): one wave per (row, slice). slice = blockIdx&1 so with
//     round-robin block->XCD dispatch each XCD gathers from ONE 3.2MB table
//     (L2-resident). If the mapping heuristic is wrong, worst case = 6.4MB in
//     2 tables per XCD — still >= unsliced-fp16 performance. Correctness never
//     depends on the mapping.
//     Lane layout: g = lane>>2 (16 edge slots), h = lane&3 (16B half8 chunk).
//     One wave-load gathers 16 edges x 64B = 1KB. fp32 accumulate; butterfly
//     reduce over g; lanes g==0 store 128B/wave. Every (row,slice) written
//     (empty rows -> 0), so no output memset.

constexpr int N_NODES = 50000;
constexpr int N_EDGES = 800000;
constexpr int D_FEAT  = 64;

using half4 = __attribute__((ext_vector_type(4))) _Float16;
using half8 = __attribute__((ext_vector_type(8))) _Float16;

// d_ws layout
constexpr size_t WS_ROWPTR_OFF = 0;                  // (N_NODES+1) ints
constexpr size_t WS_TBL0_OFF   = 4u << 20;           // 50000*32 halves = 3.2 MB
constexpr size_t WS_TBL1_OFF   = 8u << 20;

constexpr int ROWPTR_BLOCKS  = (N_EDGES + 255) / 256;        // 3125
constexpr int CONVERT_BLOCKS = (N_NODES * 16 + 255) / 256;   // 3125

__global__ __launch_bounds__(256) void prep_kernel(
    const int*   __restrict__ row_idx,
    const float* __restrict__ embeds,
    int*         __restrict__ row_ptr,
    _Float16*    __restrict__ tbl0,
    _Float16*    __restrict__ tbl1)
{
    if (blockIdx.x < ROWPTR_BLOCKS) {
        const int e = blockIdx.x * 256 + threadIdx.x;
        if (e >= N_EDGES) return;
        const int r     = row_idx[e];
        const int rprev = (e == 0) ? -1 : row_idx[e - 1];
        for (int q = rprev + 1; q <= r; ++q) row_ptr[q] = e;   // fills empty rows
        if (e == N_EDGES - 1) {
            for (int q = r + 1; q <= N_NODES; ++q) row_ptr[q] = N_EDGES;
        }
    } else {
        // fp32 -> fp16 split-convert. Thread t handles one float4 chunk.
        const int t = (blockIdx.x - ROWPTR_BLOCKS) * 256 + threadIdx.x;
        if (t >= N_NODES * 16) return;
        const int r = t >> 4;
        const int k = t & 15;                       // float4 chunk within row
        const float4 v = ((const float4*)embeds)[t];
        half4 hv;
        hv[0] = (_Float16)v.x; hv[1] = (_Float16)v.y;
        hv[2] = (_Float16)v.z; hv[3] = (_Float16)v.w;
        _Float16* tbl = (k < 8) ? tbl0 : tbl1;
        ((half4*)tbl)[r * 8 + (k & 7)] = hv;        // 8B store, contiguous rows
    }
}

__global__ __launch_bounds__(256) void gcn_spmm_kernel(
    const int*      __restrict__ row_ptr,
    const int*      __restrict__ col_idx,
    const float*    __restrict__ vals,
    const _Float16* __restrict__ tbl0,
    const _Float16* __restrict__ tbl1,
    float*          __restrict__ out)
{
    const int s   = blockIdx.x & 1;                         // slice (XCD-pinned)
    const int row = (blockIdx.x >> 1) * 4 + (threadIdx.x >> 6);
    if (row >= N_NODES) return;

    const int lane = threadIdx.x & 63;
    const int g    = lane >> 2;          // edge slot (16 per wave)
    const int h    = lane & 3;           // half8 chunk within 64B slice

    const int es = row_ptr[row];
    const int ee = row_ptr[row + 1];

    const half8* __restrict__ tbl8 =
        (const half8*)(s ? tbl1 : tbl0);  // 4 half8 per slice-row

    float acc[8] = {0.f, 0.f, 0.f, 0.f, 0.f, 0.f, 0.f, 0.f};

    for (int base = es; base < ee; base += 16) {
        const int   edge = base + g;
        const int   ce   = (edge < ee) ? edge : (ee - 1);   // clamp, in-bounds
        const int   c    = col_idx[ce];
        const float v    = (edge < ee) ? vals[ce] : 0.f;
        const half8 gv   = tbl8[c * 4 + h];                 // 16B/lane gather
#pragma unroll
        for (int i = 0; i < 8; ++i) acc[i] += v * (float)gv[i];
    }

    // Reduce over the 16 edge slots (lane bits 2..5).
#pragma unroll
    for (int mask = 4; mask <= 32; mask <<= 1) {
#pragma unroll
        for (int i = 0; i < 8; ++i) acc[i] += __shfl_xor(acc[i], mask);
    }

    if (g == 0) {
        // features [s*32 + h*8, +8): two float4 stores, 128B per wave total.
        float4* o4 = (float4*)out;
        o4[row * 16 + s * 8 + h * 2 + 0] =
            make_float4(acc[0], acc[1], acc[2], acc[3]);
        o4[row * 16 + s * 8 + h * 2 + 1] =
            make_float4(acc[4], acc[5], acc[6], acc[7]);
    }
}

extern "C" void kernel_launch(void* const* d_in, const int* in_sizes, int n_in,
                              void* d_out, int out_size, void* d_ws, size_t ws_size,
                              hipStream_t stream) {
    const int*   row_idx = (const int*)  d_in[0];
    const int*   col_idx = (const int*)  d_in[1];
    const float* vals    = (const float*)d_in[2];
    const float* embeds  = (const float*)d_in[3];
    float*       out     = (float*)      d_out;

    char* ws = (char*)d_ws;
    int*      row_ptr = (int*)     (ws + WS_ROWPTR_OFF);
    _Float16* tbl0    = (_Float16*)(ws + WS_TBL0_OFF);
    _Float16* tbl1    = (_Float16*)(ws + WS_TBL1_OFF);

    prep_kernel<<<ROWPTR_BLOCKS + CONVERT_BLOCKS, 256, 0, stream>>>(
        row_idx, embeds, row_ptr, tbl0, tbl1);

    // 2 slices x 12500 row-groups (4 rows each) = 25000 blocks.
    gcn_spmm_kernel<<<25000, 256, 0, stream>>>(row_ptr, col_idx, vals,
                                               tbl0, tbl1, out);
}

// Round 7
// 99.929 us; speedup vs baseline: 1.2908x; 1.1182x over previous
//
#include <hip/hip_runtime.h>
#include <hip/hip_fp16.h>

// SpMM: out[r, :] = sum_{e: row[e]==r} vals[e] * embeds[col[e], :]
// N_NODES=50000, N_EDGES=800000, D=64. row_idx is SORTED.
//
// R5 post-mortem: feature-splitting regressed; the wall is L2-miss gather
// traffic (~2 TB/s serve rate), and L2 residence failed because the col/val
// and output STREAMS evict table lines. R6/R7 plan:
//   - UNSLICED fp16 table: one embeds row = 64 x 2B = 128B = exactly ONE
//     cache line. Line footprint 12.8 -> 6.4 MB, gather bytes 205 -> 102 MB,
//     zero intra-line waste.
//   - Non-temporal loads for col/val and non-temporal stores for out, so the
//     only reused data (the table) keeps L2. (R7 fix: use ext_vector_type
//     floats — __builtin_nontemporal_* rejects HIP's float4 class.)
//   - One wave per row: 8 edge slots (g=lane>>3) x 8 lanes per row (h=lane&7,
//     16B half8 each). One wave-load gathers 8 edges x 128B = 1KB. Unroll x2
//     -> 16 edges (the average degree) per iteration, 2 independent gathers.
//   - fp32 accumulate; butterfly over g (xor 8/16/32); g==0 octet stores the
//     full 256B output row. Every row written -> no output memset.
// fp16 error: R5 measured absmax 0.0625 with fp16, threshold 0.29.

constexpr int N_NODES = 50000;
constexpr int N_EDGES = 800000;
constexpr int D_FEAT  = 64;

using half4 = __attribute__((ext_vector_type(4))) _Float16;
using half8 = __attribute__((ext_vector_type(8))) _Float16;
using fvec4 = __attribute__((ext_vector_type(4))) float;

// d_ws layout
constexpr size_t WS_ROWPTR_OFF = 0;          // (N_NODES+1) ints (~200 KB)
constexpr size_t WS_TBL_OFF    = 1u << 20;   // 50000*64 halves = 6.4 MB

constexpr int ROWPTR_BLOCKS  = (N_EDGES + 255) / 256;        // 3125
constexpr int CONVERT_BLOCKS = (N_NODES * 16 + 255) / 256;   // 3125

__global__ __launch_bounds__(256) void prep_kernel(
    const int*   __restrict__ row_idx,
    const float* __restrict__ embeds,
    int*         __restrict__ row_ptr,
    _Float16*    __restrict__ tbl)
{
    if (blockIdx.x < ROWPTR_BLOCKS) {
        const int e = blockIdx.x * 256 + threadIdx.x;
        if (e >= N_EDGES) return;
        const int r     = row_idx[e];
        const int rprev = (e == 0) ? -1 : row_idx[e - 1];
        for (int q = rprev + 1; q <= r; ++q) row_ptr[q] = e;   // fills empty rows
        if (e == N_EDGES - 1) {
            for (int q = r + 1; q <= N_NODES; ++q) row_ptr[q] = N_EDGES;
        }
    } else {
        // fp32 -> fp16 convert, row-major (row = 128B = one cache line).
        const int t = (blockIdx.x - ROWPTR_BLOCKS) * 256 + threadIdx.x;
        if (t >= N_NODES * 16) return;
        const fvec4 v = __builtin_nontemporal_load(((const fvec4*)embeds) + t);
        half4 hv;
        hv[0] = (_Float16)v.x; hv[1] = (_Float16)v.y;
        hv[2] = (_Float16)v.z; hv[3] = (_Float16)v.w;
        ((half4*)tbl)[t] = hv;
    }
}

__global__ __launch_bounds__(256) void gcn_spmm_kernel(
    const int*      __restrict__ row_ptr,
    const int*      __restrict__ col_idx,
    const float*    __restrict__ vals,
    const _Float16* __restrict__ tbl,
    float*          __restrict__ out)
{
    const int row = blockIdx.x * 4 + (threadIdx.x >> 6);  // one wave per row
    if (row >= N_NODES) return;

    const int lane = threadIdx.x & 63;
    const int g    = lane >> 3;          // edge slot (8 per wave-load)
    const int h    = lane & 7;           // half8 chunk within 128B row

    const int es = row_ptr[row];
    const int ee = row_ptr[row + 1];

    const half8* __restrict__ tbl8 = (const half8*)tbl;   // 8 half8 per row

    float acc[8] = {0.f, 0.f, 0.f, 0.f, 0.f, 0.f, 0.f, 0.f};

    for (int base = es; base < ee; base += 16) {
        const int e0 = base + g;
        const int e1 = base + 8 + g;
        const int c0i = (e0 < ee) ? e0 : (ee - 1);
        const int c1i = (e1 < ee) ? e1 : (ee - 1);
        // Streaming metadata: non-temporal so it doesn't evict table lines.
        const int   c0 = __builtin_nontemporal_load(col_idx + c0i);
        const int   c1 = __builtin_nontemporal_load(col_idx + c1i);
        const float v0 = (e0 < ee) ? __builtin_nontemporal_load(vals + c0i) : 0.f;
        const float v1 = (e1 < ee) ? __builtin_nontemporal_load(vals + c1i) : 0.f;
        // 2 independent 1KB wave gathers (8 edges x 128B each).
        const half8 g0 = tbl8[c0 * 8 + h];
        const half8 g1 = tbl8[c1 * 8 + h];
#pragma unroll
        for (int i = 0; i < 8; ++i) {
            acc[i] += v0 * (float)g0[i];
            acc[i] += v1 * (float)g1[i];
        }
    }

    // Reduce over the 8 edge slots (lane bits 3..5).
#pragma unroll
    for (int mask = 8; mask <= 32; mask <<= 1) {
#pragma unroll
        for (int i = 0; i < 8; ++i) acc[i] += __shfl_xor(acc[i], mask);
    }

    if (g == 0) {
        // Lane h owns floats [h*8, h*8+8) of the 256B output row.
        fvec4* o4 = (fvec4*)(out + row * D_FEAT + h * 8);
        fvec4 lo, hi;
        lo.x = acc[0]; lo.y = acc[1]; lo.z = acc[2]; lo.w = acc[3];
        hi.x = acc[4]; hi.y = acc[5]; hi.z = acc[6]; hi.w = acc[7];
        __builtin_nontemporal_store(lo, o4);
        __builtin_nontemporal_store(hi, o4 + 1);
    }
}

extern "C" void kernel_launch(void* const* d_in, const int* in_sizes, int n_in,
                              void* d_out, int out_size, void* d_ws, size_t ws_size,
                              hipStream_t stream) {
    const int*   row_idx = (const int*)  d_in[0];
    const int*   col_idx = (const int*)  d_in[1];
    const float* vals    = (const float*)d_in[2];
    const float* embeds  = (const float*)d_in[3];
    float*       out     = (float*)      d_out;

    char* ws = (char*)d_ws;
    int*      row_ptr = (int*)     (ws + WS_ROWPTR_OFF);
    _Float16* tbl     = (_Float16*)(ws + WS_TBL_OFF);

    prep_kernel<<<ROWPTR_BLOCKS + CONVERT_BLOCKS, 256, 0, stream>>>(
        row_idx, embeds, row_ptr, tbl);

    // One wave per row, 4 rows per block.
    gcn_spmm_kernel<<<(N_NODES + 3) / 4, 256, 0, stream>>>(
        row_ptr, col_idx, vals, tbl, out);
}